// Round 2
// baseline (11831.158 us; speedup 1.0000x reference)
//
#include <hip/hip_runtime.h>

// ---------- types ----------
typedef float  f32x4  __attribute__((ext_vector_type(4)));
typedef short  short8 __attribute__((ext_vector_type(8)));
typedef __bf16 bf16x8 __attribute__((ext_vector_type(8)));

#define B_SZ 2048
#define T_SZ 120
#define H_SZ 256
#define G3   768      // 3H
#define A_SZ 40

#define MFMA_BF16 __builtin_amdgcn_mfma_f32_16x16x32_bf16

union U8 { short8 s; bf16x8 b; };
__device__ __forceinline__ bf16x8 as_bf(short8 s){ U8 u; u.s = s; return u.b; }

__device__ __forceinline__ unsigned short f2bf(float x){
  unsigned u = __float_as_uint(x);
  unsigned r = (u + 0x7FFFu + ((u >> 16) & 1u)) >> 16;
  return (unsigned short)r;
}
__device__ __forceinline__ float bf2f(unsigned short h){
  return __uint_as_float(((unsigned)h) << 16);
}
__device__ __forceinline__ void cvt_hilo(float x, short& hi, short& lo){
  unsigned short h = f2bf(x);
  hi = (short)h;
  lo = (short)f2bf(x - bf2f(h));
}
__device__ __forceinline__ float sigm(float x){ return 1.0f / (1.0f + __expf(-x)); }
__device__ __forceinline__ float tanh_(float x){
  float a = fabsf(x);
  float t = 1.0f - 2.0f / (__expf(2.0f * a) + 1.0f);
  return copysignf(t, x);
}

// ---------- zero-init scratch state ----------
__global__ void zinit(float* __restrict__ p, size_t n){
  size_t i = (size_t)blockIdx.x * 256 + threadIdx.x;
  size_t stride = (size_t)gridDim.x * 256;
  for (; i < n; i += stride) p[i] = 0.0f;
}

// ---------- weight packing: W[G3 x K] fp32 -> MFMA-B bricks, bf16 hi + lo ----------
// pack[((nt*KT + kt)*64 + lane)*8 + i] = W[nt*16 + lane%16][kt*32 + (lane/16)*8 + i]
__global__ void packw_k(const float* __restrict__ W, int K,
                        short* __restrict__ hi, short* __restrict__ lo){
  int KT = K >> 5;
  int nt = blockIdx.x / KT;
  int kt = blockIdx.x % KT;
  int lane = threadIdx.x;            // 64
  int row = nt * 16 + (lane & 15);
  int col = kt * 32 + (lane >> 4) * 8;
  const float* src = W + (size_t)row * K + col;
  size_t o = (((size_t)nt * KT + kt) * 64 + lane) * 8;
#pragma unroll
  for (int i = 0; i < 8; i++){
    short h, l; cvt_hilo(src[i], h, l);
    hi[o + i] = h; lo[o + i] = l;
  }
}

// ---------- input-projection GEMM over a T-chunk ----------
// C[r, 0:768] = A_row(r) @ W^T + b1 (+ b2 for n<512), r = chunk-local row.
// If rowT != 0: A row index = (r/tcnt)*rowT + t0 + (r%tcnt); else = r.
__global__ __launch_bounds__(512, 1) void gemm3h(
    const float* __restrict__ A, int K, int rowT, int t0, int tcnt,
    const short* __restrict__ Bhi, const short* __restrict__ Blo,
    const float* __restrict__ b1, const float* __restrict__ b2,
    float* __restrict__ C)
{
  int tid = threadIdx.x;
  int wave = tid >> 6, lane = tid & 63;
  int m0 = blockIdx.x * 64 + (wave & 3) * 16;
  int nb = (wave >> 2) * 24;
  int KT = K >> 5;
  const f32x4 zero = {0.f, 0.f, 0.f, 0.f};
  f32x4 acc[24];
#pragma unroll
  for (int q = 0; q < 24; q++) acc[q] = zero;

  int r = m0 + (lane & 15);
  size_t ar;
  if (rowT){
    int b = r / tcnt;
    int tc = r - b * tcnt;
    ar = (size_t)b * rowT + t0 + tc;
  } else {
    ar = (size_t)r;
  }
  const float* Ap = A + ar * K + (lane >> 4) * 8;
  for (int kt = 0; kt < KT; ++kt){
    f32x4 a0 = *(const f32x4*)(Ap + kt * 32);
    f32x4 a1 = *(const f32x4*)(Ap + kt * 32 + 4);
    short8 ah, al;
#pragma unroll
    for (int i = 0; i < 4; i++){
      short h, l;
      cvt_hilo(a0[i], h, l); ah[i] = h;   al[i] = l;
      cvt_hilo(a1[i], h, l); ah[i+4] = h; al[i+4] = l;
    }
    bf16x8 ahb = as_bf(ah), alb = as_bf(al);
#pragma unroll
    for (int q = 0; q < 24; q++){
      size_t bo = (((size_t)(nb + q) * KT + kt) * 64 + lane) * 8;
      bf16x8 bh = as_bf(*(const short8*)(Bhi + bo));
      bf16x8 bl = as_bf(*(const short8*)(Blo + bo));
      acc[q] = MFMA_BF16(ahb, bh, acc[q], 0, 0, 0);
      acc[q] = MFMA_BF16(ahb, bl, acc[q], 0, 0, 0);
      acc[q] = MFMA_BF16(alb, bh, acc[q], 0, 0, 0);
    }
  }
  int nc = lane & 15;
  int rowb = m0 + (lane >> 4) * 4;
#pragma unroll
  for (int q = 0; q < 24; q++){
    int n = (nb + q) * 16 + nc;
    float bias = b1[n] + (n < 512 ? b2[n] : 0.0f);
#pragma unroll
    for (int i = 0; i < 4; i++)
      C[(size_t)(rowb + i) * G3 + n] = acc[q][i] + bias;
  }
}

// ---------- GRU recurrence over a T-chunk: 1 WG = 16 batch rows ----------
// h: fp32 in registers (owner thread) + bf16 hi/lo in LDS (MFMA A-operand),
// fp32 state persisted to hstate between chunks. gi/out rows are chunk-local.
__global__ __launch_bounds__(512, 1) void gru_rec(
    const float* __restrict__ gi,       // [B*tcnt, 768]
    const short* __restrict__ Whi, const short* __restrict__ Wlo,
    const float* __restrict__ bhh,      // 768; only [512..768) used (n gate)
    float* __restrict__ outp, int ldo, int ooff,
    float* __restrict__ hstate, int tcnt)
{
  __shared__ short hhi[16 * 256];   // 8 KB
  __shared__ short hlo[16 * 256];   // 8 KB
  __shared__ float ghl[16 * G3];    // 48 KB
  int tid = threadIdx.x;
  int wave = tid >> 6, lane = tid & 63;
  int b0 = blockIdx.x * 16;

  int arow = lane & 15, kgrp = lane >> 4;
  int ntb  = wave * 6;
  int hswz = (arow & 7) << 4;
  const char* hhip = (const char*)hhi + arow * 512;
  const char* hlop = (const char*)hlo + arow * 512;

  // gate-phase mapping: 16 rows x 32 col-groups of 8
  int gr = tid >> 5, jg = tid & 31, j0 = jg * 8;
  const float* gib = gi + (size_t)(b0 + gr) * tcnt * G3 + j0;
  float* outb = outp + (size_t)(b0 + gr) * tcnt * ldo + ooff + j0;
  float* hsp  = hstate + (size_t)(b0 + gr) * H_SZ + j0;
  f32x4 bn0 = *(const f32x4*)(bhh + 512 + j0);
  f32x4 bn1 = *(const f32x4*)(bhh + 512 + j0 + 4);
  int gsw = (gr & 7) << 4;
  char* hhiw = (char*)hhi + gr * 512 + ((jg * 16) ^ gsw);
  char* hlow = (char*)hlo + gr * 512 + ((jg * 16) ^ gsw);
  const f32x4 zero = {0.f, 0.f, 0.f, 0.f};

  // load h state (fp32) -> registers + LDS hi/lo
  float hreg[8];
  {
    f32x4 h0 = *(const f32x4*)hsp;
    f32x4 h1 = *(const f32x4*)(hsp + 4);
    short8 nh, nl;
#pragma unroll
    for (int i = 0; i < 8; i++){
      float v = (i < 4) ? h0[i] : h1[i - 4];
      hreg[i] = v;
      short hb, lb; cvt_hilo(v, hb, lb);
      nh[i] = hb; nl[i] = lb;
    }
    *(short8*)hhiw = nh;
    *(short8*)hlow = nl;
  }
  __syncthreads();

  for (int t = 0; t < tcnt; t++){
    f32x4 acc[6];
#pragma unroll
    for (int q = 0; q < 6; q++) acc[q] = zero;
#pragma unroll
    for (int kt = 0; kt < 8; kt++){
      int kb = (kt * 64 + kgrp * 16) ^ hswz;
      bf16x8 ah = as_bf(*(const short8*)(hhip + kb));
      bf16x8 al = as_bf(*(const short8*)(hlop + kb));
#pragma unroll
      for (int q = 0; q < 6; q++){
        size_t bo = (((size_t)(ntb + q) * 8 + kt) * 64 + lane) * 8;
        bf16x8 bh = as_bf(*(const short8*)(Whi + bo));
        bf16x8 bl = as_bf(*(const short8*)(Wlo + bo));
        acc[q] = MFMA_BF16(ah, bh, acc[q], 0, 0, 0);
        acc[q] = MFMA_BF16(ah, bl, acc[q], 0, 0, 0);
        acc[q] = MFMA_BF16(al, bh, acc[q], 0, 0, 0);
      }
    }
    // D frag: row=(lane>>4)*4+i, col=lane&15 -> gh LDS
#pragma unroll
    for (int q = 0; q < 6; q++){
      int col = (ntb + q) * 16 + arow;
#pragma unroll
      for (int i = 0; i < 4; i++)
        ghl[(kgrp * 4 + i) * G3 + col] = acc[q][i];
    }
    __syncthreads();

    // ---- gate phase (fp32) ----
    const float* gp = gib + (size_t)t * G3;
    f32x4 ir0 = *(const f32x4*)(gp);       f32x4 ir1 = *(const f32x4*)(gp + 4);
    f32x4 iz0 = *(const f32x4*)(gp + 256); f32x4 iz1 = *(const f32x4*)(gp + 260);
    f32x4 in0 = *(const f32x4*)(gp + 512); f32x4 in1 = *(const f32x4*)(gp + 516);
    const float* ghp = ghl + gr * G3 + j0;
    f32x4 hr0 = *(const f32x4*)(ghp);       f32x4 hr1 = *(const f32x4*)(ghp + 4);
    f32x4 hz0 = *(const f32x4*)(ghp + 256); f32x4 hz1 = *(const f32x4*)(ghp + 260);
    f32x4 hn0 = *(const f32x4*)(ghp + 512); f32x4 hn1 = *(const f32x4*)(ghp + 516);
    f32x4 o0, o1; short8 nh, nl;
#pragma unroll
    for (int i = 0; i < 8; i++){
      float irv = (i < 4) ? ir0[i] : ir1[i - 4];
      float izv = (i < 4) ? iz0[i] : iz1[i - 4];
      float inv_ = (i < 4) ? in0[i] : in1[i - 4];
      float hrv = (i < 4) ? hr0[i] : hr1[i - 4];
      float hzv = (i < 4) ? hz0[i] : hz1[i - 4];
      float hnv = (i < 4) ? hn0[i] : hn1[i - 4];
      float bnv = (i < 4) ? bn0[i] : bn1[i - 4];
      float rr = sigm(irv + hrv);
      float zz = sigm(izv + hzv);
      float nn = tanh_(inv_ + rr * (hnv + bnv));
      float hnew = (1.0f - zz) * nn + zz * hreg[i];
      hreg[i] = hnew;
      if (i < 4) o0[i] = hnew; else o1[i - 4] = hnew;
      short hb, lb; cvt_hilo(hnew, hb, lb);
      nh[i] = hb; nl[i] = lb;
    }
    *(short8*)hhiw = nh;
    *(short8*)hlow = nl;
    float* op = outb + (size_t)t * ldo;
    *(f32x4*)(op) = o0;
    *(f32x4*)(op + 4) = o1;
    __syncthreads();
  }

  // persist fp32 h state
  f32x4 s0, s1;
#pragma unroll
  for (int i = 0; i < 4; i++){ s0[i] = hreg[i]; s1[i] = hreg[i + 4]; }
  *(f32x4*)hsp = s0;
  *(f32x4*)(hsp + 4) = s1;
}

// ---------- attention scores for a chunk ----------
__global__ __launch_bounds__(256, 1) void attn_scores(
    const float* __restrict__ outi, const float* __restrict__ Wv,
    const float* __restrict__ bv, const float* __restrict__ wu,
    float* __restrict__ sc, int t0, int tcnt)
{
  __shared__ float swv[A_SZ * H_SZ];
  __shared__ float sbu[A_SZ], sbv[A_SZ];
  int tid = threadIdx.x;
  for (int i = tid; i < A_SZ * H_SZ; i += 256) swv[i] = Wv[i];
  if (tid < A_SZ){ sbu[tid] = wu[tid]; sbv[tid] = bv[tid]; }
  __syncthreads();
  int r = blockIdx.x * 256 + tid;      // chunk-local row
  int b = r / tcnt;
  int tc = r - b * tcnt;
  const float* x = outi + (size_t)r * H_SZ;
  float acc[A_SZ];
#pragma unroll
  for (int a = 0; a < A_SZ; a++) acc[a] = 0.f;
  for (int h = 0; h < H_SZ; h += 4){
    f32x4 xv = *(const f32x4*)(x + h);
#pragma unroll
    for (int a = 0; a < A_SZ; a++){
      f32x4 w = *(const f32x4*)(swv + a * H_SZ + h);
      acc[a] += xv[0]*w[0] + xv[1]*w[1] + xv[2]*w[2] + xv[3]*w[3];
    }
  }
  float s = 0.f;
#pragma unroll
  for (int a = 0; a < A_SZ; a++) s += sbu[a] * tanh_(acc[a] + sbv[a]);
  sc[(size_t)b * T_SZ + t0 + tc] = s;
}

// ---------- online (unnormalized) context accumulation ----------
// |score| <= sum|wu| ~ 1.6 so exp() is safe without max-subtraction.
__global__ __launch_bounds__(256, 1) void attn_acc(
    const float* __restrict__ outi, const float* __restrict__ sc,
    int t0, int tcnt, float* __restrict__ ctx, float* __restrict__ lsum)
{
  int b = blockIdx.x, tid = threadIdx.x;
  float acc = ctx[(size_t)b * H_SZ + tid];
  const float* xp = outi + (size_t)b * tcnt * H_SZ + tid;
  float ls = 0.f;
  for (int tc = 0; tc < tcnt; tc++){
    float e = __expf(sc[(size_t)b * T_SZ + t0 + tc]);
    acc += e * xp[(size_t)tc * H_SZ];
    ls += e;
  }
  ctx[(size_t)b * H_SZ + tid] = acc;
  if (tid == 0) lsum[b] += ls;
}

__global__ __launch_bounds__(256, 1) void attn_fin(
    const float* __restrict__ ctx, const float* __restrict__ lsum,
    float* __restrict__ out)
{
  int b = blockIdx.x, tid = threadIdx.x;
  out[(size_t)b * H_SZ + tid] = ctx[(size_t)b * H_SZ + tid] / lsum[b];
}

// ---------- host ----------
extern "C" void kernel_launch(void* const* d_in, const int* in_sizes, int n_in,
                              void* d_out, int out_size, void* d_ws, size_t ws_size,
                              hipStream_t stream)
{
  (void)in_sizes; (void)n_in; (void)out_size;
  const float* crime = (const float*)d_in[0];
  const float* anom  = (const float*)d_in[1];
  const float* WihC = (const float*)d_in[2];
  const float* WhhC = (const float*)d_in[3];
  const float* bihC = (const float*)d_in[4];
  const float* bhhC = (const float*)d_in[5];
  const float* WihA = (const float*)d_in[6];
  const float* WhhA = (const float*)d_in[7];
  const float* bihA = (const float*)d_in[8];
  const float* bhhA = (const float*)d_in[9];
  const float* WihI = (const float*)d_in[10];
  const float* WhhI = (const float*)d_in[11];
  const float* bihI = (const float*)d_in[12];
  const float* bhhI = (const float*)d_in[13];
  const float* Wv = (const float*)d_in[14];
  const float* bv = (const float*)d_in[15];
  const float* wu = (const float*)d_in[16];
  float* out = (float*)d_out;

  char* ws = (char*)d_ws;
  size_t off = 0;
  auto take = [&](size_t n){ size_t r = off; off += (n + 255) & ~(size_t)255; return r; };

  short* pWihC_h = (short*)(ws + take((size_t)G3 * 128 * 2));
  short* pWihC_l = (short*)(ws + take((size_t)G3 * 128 * 2));
  short* pWhhC_h = (short*)(ws + take((size_t)G3 * 256 * 2));
  short* pWhhC_l = (short*)(ws + take((size_t)G3 * 256 * 2));
  short* pWihA_h = (short*)(ws + take((size_t)G3 * 96 * 2));
  short* pWihA_l = (short*)(ws + take((size_t)G3 * 96 * 2));
  short* pWhhA_h = (short*)(ws + take((size_t)G3 * 256 * 2));
  short* pWhhA_l = (short*)(ws + take((size_t)G3 * 256 * 2));
  short* pWihI_h = (short*)(ws + take((size_t)G3 * 512 * 2));
  short* pWihI_l = (short*)(ws + take((size_t)G3 * 512 * 2));
  short* pWhhI_h = (short*)(ws + take((size_t)G3 * 256 * 2));
  short* pWhhI_l = (short*)(ws + take((size_t)G3 * 256 * 2));
  float* scores  = (float*)(ws + take((size_t)B_SZ * T_SZ * 4));

  size_t state_off = off;
  float* hsC  = (float*)(ws + take((size_t)B_SZ * H_SZ * 4));
  float* hsA  = (float*)(ws + take((size_t)B_SZ * H_SZ * 4));
  float* hsI  = (float*)(ws + take((size_t)B_SZ * H_SZ * 4));
  float* ctx  = (float*)(ws + take((size_t)B_SZ * H_SZ * 4));
  float* lsum = (float*)(ws + take((size_t)B_SZ * 4));
  size_t state_end = off;

  // adaptive T-chunk: fit G + Oca + Oi into remaining workspace
  size_t per = (size_t)B_SZ * 4 * (G3 + 512 + H_SZ);   // 12.58 MB per timestep
  size_t avail = (ws_size > off + 4096) ? (ws_size - off - 4096) : 0;
  int TC = (int)(avail / per);
  if (TC < 1) TC = 1;
  if (TC > T_SZ) TC = T_SZ;

  float* G   = (float*)(ws + take((size_t)B_SZ * TC * G3 * 4));
  float* Oca = (float*)(ws + take((size_t)B_SZ * TC * 512 * 4));
  float* Oi  = (float*)(ws + take((size_t)B_SZ * TC * H_SZ * 4));

  // zero h-states, ctx, lsum
  zinit<<<2048, 256, 0, stream>>>((float*)(ws + state_off), (state_end - state_off) / 4);

  // pack weights (hi/lo bricks)
  packw_k<<<48 * 4,  64, 0, stream>>>(WihC, 128, pWihC_h, pWihC_l);
  packw_k<<<48 * 8,  64, 0, stream>>>(WhhC, 256, pWhhC_h, pWhhC_l);
  packw_k<<<48 * 3,  64, 0, stream>>>(WihA,  96, pWihA_h, pWihA_l);
  packw_k<<<48 * 8,  64, 0, stream>>>(WhhA, 256, pWhhA_h, pWhhA_l);
  packw_k<<<48 * 16, 64, 0, stream>>>(WihI, 512, pWihI_h, pWihI_l);
  packw_k<<<48 * 8,  64, 0, stream>>>(WhhI, 256, pWhhI_h, pWhhI_l);

  for (int t0 = 0; t0 < T_SZ; ){
    int tcnt = T_SZ - t0 < TC ? T_SZ - t0 : TC;
    int rows = B_SZ * tcnt;
    // crime -> out_c (Oca[:, 0:256])
    gemm3h<<<rows / 64, 512, 0, stream>>>(crime, 128, T_SZ, t0, tcnt,
                                          pWihC_h, pWihC_l, bihC, bhhC, G);
    gru_rec<<<128, 512, 0, stream>>>(G, pWhhC_h, pWhhC_l, bhhC, Oca, 512, 0, hsC, tcnt);
    // anomaly -> out_a (Oca[:, 256:512])
    gemm3h<<<rows / 64, 512, 0, stream>>>(anom, 96, T_SZ, t0, tcnt,
                                          pWihA_h, pWihA_l, bihA, bhhA, G);
    gru_rec<<<128, 512, 0, stream>>>(G, pWhhA_h, pWhhA_l, bhhA, Oca, 512, 256, hsA, tcnt);
    // inter: gi from [out_c|out_a] -> out_i
    gemm3h<<<rows / 64, 512, 0, stream>>>(Oca, 512, 0, 0, tcnt,
                                          pWihI_h, pWihI_l, bihI, bhhI, G);
    gru_rec<<<128, 512, 0, stream>>>(G, pWhhI_h, pWhhI_l, bhhI, Oi, 256, 0, hsI, tcnt);
    // attention: scores + online context accumulation
    attn_scores<<<rows / 256, 256, 0, stream>>>(Oi, Wv, bv, wu, scores, t0, tcnt);
    attn_acc<<<B_SZ, 256, 0, stream>>>(Oi, scores, t0, tcnt, ctx, lsum);
    t0 += tcnt;
  }
  attn_fin<<<B_SZ, 256, 0, stream>>>(ctx, lsum, out);
}

// Round 3
// 7907.491 us; speedup vs baseline: 1.4962x; 1.4962x over previous
//
#include <hip/hip_runtime.h>

// ---------- types ----------
typedef float  f32x4  __attribute__((ext_vector_type(4)));
typedef short  short8 __attribute__((ext_vector_type(8)));
typedef __bf16 bf16x8 __attribute__((ext_vector_type(8)));

#define B_SZ 2048
#define T_SZ 120
#define H_SZ 256
#define G3   768      // 3H
#define A_SZ 40

#define MFMA_BF16 __builtin_amdgcn_mfma_f32_16x16x32_bf16

union U8 { short8 s; bf16x8 b; };
__device__ __forceinline__ bf16x8 as_bf(short8 s){ U8 u; u.s = s; return u.b; }

__device__ __forceinline__ unsigned short f2bf(float x){
  unsigned u = __float_as_uint(x);
  unsigned r = (u + 0x7FFFu + ((u >> 16) & 1u)) >> 16;
  return (unsigned short)r;
}
__device__ __forceinline__ float bf2f(unsigned short h){
  return __uint_as_float(((unsigned)h) << 16);
}
__device__ __forceinline__ void cvt_hilo(float x, short& hi, short& lo){
  unsigned short h = f2bf(x);
  hi = (short)h;
  lo = (short)f2bf(x - bf2f(h));
}
__device__ __forceinline__ float sigm(float x){ return 1.0f / (1.0f + __expf(-x)); }
__device__ __forceinline__ float tanh_(float x){
  float a = fabsf(x);
  float t = 1.0f - 2.0f / (__expf(2.0f * a) + 1.0f);
  return copysignf(t, x);
}

// ---------- zero-init scratch state ----------
__global__ void zinit(float* __restrict__ p, size_t n){
  size_t i = (size_t)blockIdx.x * 256 + threadIdx.x;
  size_t stride = (size_t)gridDim.x * 256;
  for (; i < n; i += stride) p[i] = 0.0f;
}

// ---------- weight packing: W[G3 x K] fp32 -> MFMA-B bricks, bf16 hi + lo ----------
// pack[((nt*KT + kt)*64 + lane)*8 + i] = W[nt*16 + lane%16][kt*32 + (lane/16)*8 + i]
__global__ void packw_k(const float* __restrict__ W, int K,
                        short* __restrict__ hi, short* __restrict__ lo){
  int KT = K >> 5;
  int nt = blockIdx.x / KT;
  int kt = blockIdx.x % KT;
  int lane = threadIdx.x;            // 64
  int row = nt * 16 + (lane & 15);
  int col = kt * 32 + (lane >> 4) * 8;
  const float* src = W + (size_t)row * K + col;
  size_t o = (((size_t)nt * KT + kt) * 64 + lane) * 8;
#pragma unroll
  for (int i = 0; i < 8; i++){
    short h, l; cvt_hilo(src[i], h, l);
    hi[o + i] = h; lo[o + i] = l;
  }
}

// ---------- input-projection GEMM over a T-chunk (3-pass split-bf16) ----------
// C[r, 0:768] = A_row(r) @ W^T + b1 (+ b2 for n<512), r = chunk-local row.
// If rowT != 0: A row index = (r/tcnt)*rowT + t0 + (r%tcnt); else = r.
__global__ __launch_bounds__(512, 1) void gemm3h(
    const float* __restrict__ A, int K, int rowT, int t0, int tcnt,
    const short* __restrict__ Bhi, const short* __restrict__ Blo,
    const float* __restrict__ b1, const float* __restrict__ b2,
    float* __restrict__ C)
{
  int tid = threadIdx.x;
  int wave = tid >> 6, lane = tid & 63;
  int m0 = blockIdx.x * 64 + (wave & 3) * 16;
  int nb = (wave >> 2) * 24;
  int KT = K >> 5;
  const f32x4 zero = {0.f, 0.f, 0.f, 0.f};
  f32x4 acc[24];
#pragma unroll
  for (int q = 0; q < 24; q++) acc[q] = zero;

  int r = m0 + (lane & 15);
  size_t ar;
  if (rowT){
    int b = r / tcnt;
    int tc = r - b * tcnt;
    ar = (size_t)b * rowT + t0 + tc;
  } else {
    ar = (size_t)r;
  }
  const float* Ap = A + ar * K + (lane >> 4) * 8;
  for (int kt = 0; kt < KT; ++kt){
    f32x4 a0 = *(const f32x4*)(Ap + kt * 32);
    f32x4 a1 = *(const f32x4*)(Ap + kt * 32 + 4);
    short8 ah, al;
#pragma unroll
    for (int i = 0; i < 4; i++){
      short h, l;
      cvt_hilo(a0[i], h, l); ah[i] = h;   al[i] = l;
      cvt_hilo(a1[i], h, l); ah[i+4] = h; al[i+4] = l;
    }
    bf16x8 ahb = as_bf(ah), alb = as_bf(al);
#pragma unroll
    for (int q = 0; q < 24; q++){
      size_t bo = (((size_t)(nb + q) * KT + kt) * 64 + lane) * 8;
      bf16x8 bh = as_bf(*(const short8*)(Bhi + bo));
      bf16x8 bl = as_bf(*(const short8*)(Blo + bo));
      acc[q] = MFMA_BF16(ahb, bh, acc[q], 0, 0, 0);
      acc[q] = MFMA_BF16(ahb, bl, acc[q], 0, 0, 0);
      acc[q] = MFMA_BF16(alb, bh, acc[q], 0, 0, 0);
    }
  }
  int nc = lane & 15;
  int rowb = m0 + (lane >> 4) * 4;
#pragma unroll
  for (int q = 0; q < 24; q++){
    int n = (nb + q) * 16 + nc;
    float bias = b1[n] + (n < 512 ? b2[n] : 0.0f);
#pragma unroll
    for (int i = 0; i < 4; i++)
      C[(size_t)(rowb + i) * G3 + n] = acc[q][i] + bias;
  }
}

// ---------- GRU recurrence v2: 1 WG = 16 batch rows, register gates ----------
// Wave w owns ntiles {w, w+8, ..., w+40}: lane holds complete (r,z,n) triples
// for its 8 h-elements -> gate math in registers, no gh LDS roundtrip.
// h: fp32 in owner-lane registers; bf16 hi/lo double-buffered in LDS (A-operand).
// W_hh: bf16-hi only (2-pass MFMA: ah*bh + al*bh).
__global__ __launch_bounds__(512, 1) void gru_rec(
    const float* __restrict__ gi,       // [B*tcnt, 768]
    const short* __restrict__ Whi,
    const float* __restrict__ bhh,      // 768; only [512..768) used (n gate)
    float* __restrict__ outp, int ldo, int ooff,
    float* __restrict__ hstate, int tcnt)
{
  __shared__ short hhi[2][16 * 256];   // 8 KB each
  __shared__ short hlo[2][16 * 256];
  int tid = threadIdx.x;
  int w = tid >> 6, lane = tid & 63;
  int arow = lane & 15, kgrp = lane >> 4;
  int b0 = blockIdx.x * 16;
  int c0 = w * 16 + arow;              // h-col for j=0; j=1 -> c0+128
  int hswz = (arow & 7) << 4;

  // n-gate bias for my two cols
  float bn0 = bhh[512 + c0];
  float bn1 = bhh[512 + c0 + 128];

  // per-row pointers (rows = kgrp*4 + i)
  const float* gp[4];
  float* op[4];
  float* hp[4];
#pragma unroll
  for (int i = 0; i < 4; i++){
    int row = b0 + kgrp * 4 + i;
    gp[i] = gi + (size_t)row * tcnt * G3;
    op[i] = outp + (size_t)row * tcnt * ldo + ooff;
    hp[i] = hstate + (size_t)row * H_SZ;
  }

  // h registers + initial LDS fill (buf 0)
  float hreg[2][4];
#pragma unroll
  for (int j = 0; j < 2; j++)
#pragma unroll
    for (int i = 0; i < 4; i++){
      float v = hp[i][c0 + j * 128];
      hreg[j][i] = v;
      int r = kgrp * 4 + i;
      int off = ((c0 + j * 128) * 2) ^ ((r & 7) << 4);
      short h_, l_; cvt_hilo(v, h_, l_);
      *(short*)((char*)hhi[0] + r * 512 + off) = h_;
      *(short*)((char*)hlo[0] + r * 512 + off) = l_;
    }
  __syncthreads();

  const f32x4 zero = {0.f, 0.f, 0.f, 0.f};
  int cur = 0;
  for (int t = 0; t < tcnt; t++){
    // ---- issue gi loads early (hide under MFMA phase) ----
    float gr_[2][4], gz_[2][4], gn_[2][4];
#pragma unroll
    for (int j = 0; j < 2; j++)
#pragma unroll
      for (int i = 0; i < 4; i++){
        const float* g = gp[i] + (size_t)t * G3 + c0 + j * 128;
        gr_[j][i] = g[0];
        gz_[j][i] = g[256];
        gn_[j][i] = g[512];
      }

    // ---- MFMA phase: gh for my 6 ntiles (2-pass: h_hi*W + h_lo*W) ----
    f32x4 acc[6];
#pragma unroll
    for (int q = 0; q < 6; q++) acc[q] = zero;
    const char* hhip = (const char*)hhi[cur] + arow * 512;
    const char* hlop = (const char*)hlo[cur] + arow * 512;
#pragma unroll
    for (int kt = 0; kt < 8; kt++){
      int kb = (kt * 64 + kgrp * 16) ^ hswz;
      bf16x8 ah = as_bf(*(const short8*)(hhip + kb));
      bf16x8 al = as_bf(*(const short8*)(hlop + kb));
#pragma unroll
      for (int q = 0; q < 6; q++){
        int bo = (((w + 8 * q) * 8 + kt) * 64 + lane) * 8;
        bf16x8 bh = as_bf(*(const short8*)(Whi + bo));
        acc[q] = MFMA_BF16(ah, bh, acc[q], 0, 0, 0);
        acc[q] = MFMA_BF16(al, bh, acc[q], 0, 0, 0);
      }
    }

    // ---- gate math in registers; write h_new to LDS buf cur^1 ----
    int nb = cur ^ 1;
#pragma unroll
    for (int j = 0; j < 2; j++)
#pragma unroll
      for (int i = 0; i < 4; i++){
        float rr = sigm(gr_[j][i] + acc[0 + j][i]);
        float zz = sigm(gz_[j][i] + acc[2 + j][i]);
        float bn = j ? bn1 : bn0;
        float nn = tanh_(gn_[j][i] + rr * (acc[4 + j][i] + bn));
        float hnew = (1.0f - zz) * nn + zz * hreg[j][i];
        hreg[j][i] = hnew;
        op[i][(size_t)t * ldo + c0 + j * 128] = hnew;
        int r = kgrp * 4 + i;
        int off = ((c0 + j * 128) * 2) ^ ((r & 7) << 4);
        short h_, l_; cvt_hilo(hnew, h_, l_);
        *(short*)((char*)hhi[nb] + r * 512 + off) = h_;
        *(short*)((char*)hlo[nb] + r * 512 + off) = l_;
      }
    __syncthreads();
    cur ^= 1;
  }

  // persist fp32 h state
#pragma unroll
  for (int j = 0; j < 2; j++)
#pragma unroll
    for (int i = 0; i < 4; i++)
      hp[i][c0 + j * 128] = hreg[j][i];
}

// ---------- attention scores for a chunk ----------
__global__ __launch_bounds__(256, 1) void attn_scores(
    const float* __restrict__ outi, const float* __restrict__ Wv,
    const float* __restrict__ bv, const float* __restrict__ wu,
    float* __restrict__ sc, int t0, int tcnt)
{
  __shared__ float swv[A_SZ * H_SZ];
  __shared__ float sbu[A_SZ], sbv[A_SZ];
  int tid = threadIdx.x;
  for (int i = tid; i < A_SZ * H_SZ; i += 256) swv[i] = Wv[i];
  if (tid < A_SZ){ sbu[tid] = wu[tid]; sbv[tid] = bv[tid]; }
  __syncthreads();
  int r = blockIdx.x * 256 + tid;      // chunk-local row
  int b = r / tcnt;
  int tc = r - b * tcnt;
  const float* x = outi + (size_t)r * H_SZ;
  float acc[A_SZ];
#pragma unroll
  for (int a = 0; a < A_SZ; a++) acc[a] = 0.f;
  for (int h = 0; h < H_SZ; h += 4){
    f32x4 xv = *(const f32x4*)(x + h);
#pragma unroll
    for (int a = 0; a < A_SZ; a++){
      f32x4 w = *(const f32x4*)(swv + a * H_SZ + h);
      acc[a] += xv[0]*w[0] + xv[1]*w[1] + xv[2]*w[2] + xv[3]*w[3];
    }
  }
  float s = 0.f;
#pragma unroll
  for (int a = 0; a < A_SZ; a++) s += sbu[a] * tanh_(acc[a] + sbv[a]);
  sc[(size_t)b * T_SZ + t0 + tc] = s;
}

// ---------- online (unnormalized) context accumulation ----------
// |score| <= sum|wu| ~ 1.6 so exp() is safe without max-subtraction.
__global__ __launch_bounds__(256, 1) void attn_acc(
    const float* __restrict__ outi, const float* __restrict__ sc,
    int t0, int tcnt, float* __restrict__ ctx, float* __restrict__ lsum)
{
  int b = blockIdx.x, tid = threadIdx.x;
  float acc = ctx[(size_t)b * H_SZ + tid];
  const float* xp = outi + (size_t)b * tcnt * H_SZ + tid;
  float ls = 0.f;
  for (int tc = 0; tc < tcnt; tc++){
    float e = __expf(sc[(size_t)b * T_SZ + t0 + tc]);
    acc += e * xp[(size_t)tc * H_SZ];
    ls += e;
  }
  ctx[(size_t)b * H_SZ + tid] = acc;
  if (tid == 0) lsum[b] += ls;
}

__global__ __launch_bounds__(256, 1) void attn_fin(
    const float* __restrict__ ctx, const float* __restrict__ lsum,
    float* __restrict__ out)
{
  int b = blockIdx.x, tid = threadIdx.x;
  out[(size_t)b * H_SZ + tid] = ctx[(size_t)b * H_SZ + tid] / lsum[b];
}

// ---------- host ----------
extern "C" void kernel_launch(void* const* d_in, const int* in_sizes, int n_in,
                              void* d_out, int out_size, void* d_ws, size_t ws_size,
                              hipStream_t stream)
{
  (void)in_sizes; (void)n_in; (void)out_size;
  const float* crime = (const float*)d_in[0];
  const float* anom  = (const float*)d_in[1];
  const float* WihC = (const float*)d_in[2];
  const float* WhhC = (const float*)d_in[3];
  const float* bihC = (const float*)d_in[4];
  const float* bhhC = (const float*)d_in[5];
  const float* WihA = (const float*)d_in[6];
  const float* WhhA = (const float*)d_in[7];
  const float* bihA = (const float*)d_in[8];
  const float* bhhA = (const float*)d_in[9];
  const float* WihI = (const float*)d_in[10];
  const float* WhhI = (const float*)d_in[11];
  const float* bihI = (const float*)d_in[12];
  const float* bhhI = (const float*)d_in[13];
  const float* Wv = (const float*)d_in[14];
  const float* bv = (const float*)d_in[15];
  const float* wu = (const float*)d_in[16];
  float* out = (float*)d_out;

  char* ws = (char*)d_ws;
  size_t off = 0;
  auto take = [&](size_t n){ size_t r = off; off += (n + 255) & ~(size_t)255; return r; };

  short* pWihC_h = (short*)(ws + take((size_t)G3 * 128 * 2));
  short* pWihC_l = (short*)(ws + take((size_t)G3 * 128 * 2));
  short* pWhhC_h = (short*)(ws + take((size_t)G3 * 256 * 2));
  short* pWhhC_l = (short*)(ws + take((size_t)G3 * 256 * 2));
  short* pWihA_h = (short*)(ws + take((size_t)G3 * 96 * 2));
  short* pWihA_l = (short*)(ws + take((size_t)G3 * 96 * 2));
  short* pWhhA_h = (short*)(ws + take((size_t)G3 * 256 * 2));
  short* pWhhA_l = (short*)(ws + take((size_t)G3 * 256 * 2));
  short* pWihI_h = (short*)(ws + take((size_t)G3 * 512 * 2));
  short* pWihI_l = (short*)(ws + take((size_t)G3 * 512 * 2));
  short* pWhhI_h = (short*)(ws + take((size_t)G3 * 256 * 2));
  short* pWhhI_l = (short*)(ws + take((size_t)G3 * 256 * 2));
  float* scores  = (float*)(ws + take((size_t)B_SZ * T_SZ * 4));

  size_t state_off = off;
  float* hsC  = (float*)(ws + take((size_t)B_SZ * H_SZ * 4));
  float* hsA  = (float*)(ws + take((size_t)B_SZ * H_SZ * 4));
  float* hsI  = (float*)(ws + take((size_t)B_SZ * H_SZ * 4));
  float* ctx  = (float*)(ws + take((size_t)B_SZ * H_SZ * 4));
  float* lsum = (float*)(ws + take((size_t)B_SZ * 4));
  size_t state_end = off;

  // adaptive T-chunk: fit G + Oca + Oi into remaining workspace
  size_t per = (size_t)B_SZ * 4 * (G3 + 512 + H_SZ);   // 12.58 MB per timestep
  size_t avail = (ws_size > off + 4096) ? (ws_size - off - 4096) : 0;
  int TC = (int)(avail / per);
  if (TC < 1) TC = 1;
  if (TC > T_SZ) TC = T_SZ;

  float* G   = (float*)(ws + take((size_t)B_SZ * TC * G3 * 4));
  float* Oca = (float*)(ws + take((size_t)B_SZ * TC * 512 * 4));
  float* Oi  = (float*)(ws + take((size_t)B_SZ * TC * H_SZ * 4));

  // zero h-states, ctx, lsum
  zinit<<<2048, 256, 0, stream>>>((float*)(ws + state_off), (state_end - state_off) / 4);

  // pack weights (hi/lo bricks)
  packw_k<<<48 * 4,  64, 0, stream>>>(WihC, 128, pWihC_h, pWihC_l);
  packw_k<<<48 * 8,  64, 0, stream>>>(WhhC, 256, pWhhC_h, pWhhC_l);
  packw_k<<<48 * 3,  64, 0, stream>>>(WihA,  96, pWihA_h, pWihA_l);
  packw_k<<<48 * 8,  64, 0, stream>>>(WhhA, 256, pWhhA_h, pWhhA_l);
  packw_k<<<48 * 16, 64, 0, stream>>>(WihI, 512, pWihI_h, pWihI_l);
  packw_k<<<48 * 8,  64, 0, stream>>>(WhhI, 256, pWhhI_h, pWhhI_l);

  for (int t0 = 0; t0 < T_SZ; ){
    int tcnt = T_SZ - t0 < TC ? T_SZ - t0 : TC;
    int rows = B_SZ * tcnt;
    // crime -> out_c (Oca[:, 0:256])
    gemm3h<<<rows / 64, 512, 0, stream>>>(crime, 128, T_SZ, t0, tcnt,
                                          pWihC_h, pWihC_l, bihC, bhhC, G);
    gru_rec<<<128, 512, 0, stream>>>(G, pWhhC_h, bhhC, Oca, 512, 0, hsC, tcnt);
    // anomaly -> out_a (Oca[:, 256:512])
    gemm3h<<<rows / 64, 512, 0, stream>>>(anom, 96, T_SZ, t0, tcnt,
                                          pWihA_h, pWihA_l, bihA, bhhA, G);
    gru_rec<<<128, 512, 0, stream>>>(G, pWhhA_h, bhhA, Oca, 512, 256, hsA, tcnt);
    // inter: gi from [out_c|out_a] -> out_i
    gemm3h<<<rows / 64, 512, 0, stream>>>(Oca, 512, 0, 0, tcnt,
                                          pWihI_h, pWihI_l, bihI, bhhI, G);
    gru_rec<<<128, 512, 0, stream>>>(G, pWhhI_h, bhhI, Oi, 256, 0, hsI, tcnt);
    // attention: scores + online context accumulation
    attn_scores<<<rows / 256, 256, 0, stream>>>(Oi, Wv, bv, wu, scores, t0, tcnt);
    attn_acc<<<B_SZ, 256, 0, stream>>>(Oi, scores, t0, tcnt, ctx, lsum);
    t0 += tcnt;
  }
  attn_fin<<<B_SZ, 256, 0, stream>>>(ctx, lsum, out);
}

// Round 4
// 5761.401 us; speedup vs baseline: 2.0535x; 1.3725x over previous
//
#include <hip/hip_runtime.h>

// ---------- types ----------
typedef float  f32x4  __attribute__((ext_vector_type(4)));
typedef short  short8 __attribute__((ext_vector_type(8)));
typedef __bf16 bf16x8 __attribute__((ext_vector_type(8)));

#define B_SZ 2048
#define T_SZ 120
#define H_SZ 256
#define G3   768      // 3H
#define A_SZ 40

#define MFMA_BF16 __builtin_amdgcn_mfma_f32_16x16x32_bf16

union U8 { short8 s; bf16x8 b; };
__device__ __forceinline__ bf16x8 as_bf(short8 s){ U8 u; u.s = s; return u.b; }

__device__ __forceinline__ unsigned short f2bf(float x){
  unsigned u = __float_as_uint(x);
  unsigned r = (u + 0x7FFFu + ((u >> 16) & 1u)) >> 16;
  return (unsigned short)r;
}
__device__ __forceinline__ float bf2f(unsigned short h){
  return __uint_as_float(((unsigned)h) << 16);
}
__device__ __forceinline__ void cvt_hilo(float x, short& hi, short& lo){
  unsigned short h = f2bf(x);
  hi = (short)h;
  lo = (short)f2bf(x - bf2f(h));
}
__device__ __forceinline__ float sigm(float x){ return 1.0f / (1.0f + __expf(-x)); }
__device__ __forceinline__ float tanh_(float x){
  float a = fabsf(x);
  float t = 1.0f - 2.0f / (__expf(2.0f * a) + 1.0f);
  return copysignf(t, x);
}

// ---------- zero-init scratch state ----------
__global__ void zinit(float* __restrict__ p, size_t n){
  size_t i = (size_t)blockIdx.x * 256 + threadIdx.x;
  size_t stride = (size_t)gridDim.x * 256;
  for (; i < n; i += stride) p[i] = 0.0f;
}

// ---------- weight packing: W[G3 x K] fp32 -> MFMA-B bricks, bf16 hi + lo ----------
// pack[((nt*KT + kt)*64 + lane)*8 + i] = W[nt*16 + lane%16][kt*32 + (lane/16)*8 + i]
__global__ void packw_k(const float* __restrict__ W, int K,
                        short* __restrict__ hi, short* __restrict__ lo){
  int KT = K >> 5;
  int nt = blockIdx.x / KT;
  int kt = blockIdx.x % KT;
  int lane = threadIdx.x;            // 64
  int row = nt * 16 + (lane & 15);
  int col = kt * 32 + (lane >> 4) * 8;
  const float* src = W + (size_t)row * K + col;
  size_t o = (((size_t)nt * KT + kt) * 64 + lane) * 8;
#pragma unroll
  for (int i = 0; i < 8; i++){
    short h, l; cvt_hilo(src[i], h, l);
    hi[o + i] = h; lo[o + i] = l;
  }
}

// ---------- input-projection GEMM v2: 2-pass (A split hi/lo, B hi only) ----------
// Wave tile M=32 (2 A-frags) x N=192 (12 ntiles); WG = 8 waves -> M=64, N=768.
// If rowT != 0: A row index = (r/tcnt)*rowT + t0 + (r%tcnt); else = r.
__global__ __launch_bounds__(512, 1) void gemm2p(
    const float* __restrict__ A, int K, int rowT, int t0, int tcnt,
    const short* __restrict__ Bhi,
    const float* __restrict__ b1, const float* __restrict__ b2,
    float* __restrict__ C)
{
  int tid = threadIdx.x;
  int w = tid >> 6, lane = tid & 63;
  int mg = w & 1, ng = w >> 1;         // ng 0..3
  int m0 = blockIdx.x * 64 + mg * 32;
  int nb = ng * 12;
  int KT = K >> 5;
  const f32x4 zero = {0.f, 0.f, 0.f, 0.f};
  f32x4 acc[2][12];
#pragma unroll
  for (int f = 0; f < 2; f++)
#pragma unroll
    for (int q = 0; q < 12; q++) acc[f][q] = zero;

  int rr = lane & 15, ks = lane >> 4;
  const float* Ap[2];
#pragma unroll
  for (int f = 0; f < 2; f++){
    int r = m0 + f * 16 + rr;
    size_t ar;
    if (rowT){
      int b = r / tcnt;
      int tc = r - b * tcnt;
      ar = (size_t)b * rowT + t0 + tc;
    } else {
      ar = (size_t)r;
    }
    Ap[f] = A + ar * K + ks * 8;
  }

  for (int kt = 0; kt < KT; ++kt){
    bf16x8 ahb[2], alb[2];
#pragma unroll
    for (int f = 0; f < 2; f++){
      f32x4 a0 = *(const f32x4*)(Ap[f] + kt * 32);
      f32x4 a1 = *(const f32x4*)(Ap[f] + kt * 32 + 4);
      short8 ah, al;
#pragma unroll
      for (int i = 0; i < 4; i++){
        short h, l;
        cvt_hilo(a0[i], h, l); ah[i] = h;   al[i] = l;
        cvt_hilo(a1[i], h, l); ah[i+4] = h; al[i+4] = l;
      }
      ahb[f] = as_bf(ah); alb[f] = as_bf(al);
    }
#pragma unroll
    for (int q = 0; q < 12; q++){
      int bo = (((nb + q) * KT + kt) * 64 + lane) * 8;
      bf16x8 bh = as_bf(*(const short8*)(Bhi + bo));
#pragma unroll
      for (int f = 0; f < 2; f++){
        acc[f][q] = MFMA_BF16(ahb[f], bh, acc[f][q], 0, 0, 0);
        acc[f][q] = MFMA_BF16(alb[f], bh, acc[f][q], 0, 0, 0);
      }
    }
  }
  int nc = lane & 15;
  int rb = lane >> 4;
#pragma unroll
  for (int q = 0; q < 12; q++){
    int n = (nb + q) * 16 + nc;
    float bias = b1[n] + (n < 512 ? b2[n] : 0.0f);
#pragma unroll
    for (int f = 0; f < 2; f++)
#pragma unroll
      for (int i = 0; i < 4; i++)
        C[(size_t)(m0 + f * 16 + rb * 4 + i) * G3 + n] = acc[f][q][i] + bias;
  }
}

// ---------- GRU recurrence (fused dual): 1 WG = 16 batch rows ----------
// blockIdx < nwg0 -> stream 0 (e.g. crime), else stream 1 (anomaly).
// Wave w owns ntiles {w, w+8, ..., w+40}: gate math fully in registers.
// h fp32 in owner-lane regs; bf16 hi/lo double-buffered LDS; W bf16-hi only.
__global__ __launch_bounds__(512, 1) void gru_rec2(
    const float* __restrict__ gi0, const short* __restrict__ W0,
    const float* __restrict__ bhh0, float* __restrict__ out0, int ldo0, int ooff0,
    float* __restrict__ hs0,
    const float* __restrict__ gi1, const short* __restrict__ W1,
    const float* __restrict__ bhh1, float* __restrict__ out1, int ldo1, int ooff1,
    float* __restrict__ hs1,
    int nwg0, int tcnt)
{
  __shared__ short hhi[2][16 * 256];   // 8 KB each
  __shared__ short hlo[2][16 * 256];
  int wg = blockIdx.x;
  const float* gi; const short* Whi; const float* bhh;
  float* outp; int ldo, ooff; float* hstate; int b0;
  if (wg < nwg0){
    gi = gi0; Whi = W0; bhh = bhh0; outp = out0; ldo = ldo0; ooff = ooff0;
    hstate = hs0; b0 = wg * 16;
  } else {
    gi = gi1; Whi = W1; bhh = bhh1; outp = out1; ldo = ldo1; ooff = ooff1;
    hstate = hs1; b0 = (wg - nwg0) * 16;
  }

  int tid = threadIdx.x;
  int w = tid >> 6, lane = tid & 63;
  int arow = lane & 15, kgrp = lane >> 4;
  int c0 = w * 16 + arow;              // h-col for j=0; j=1 -> c0+128
  int hswz = (arow & 7) << 4;

  float bn0 = bhh[512 + c0];
  float bn1 = bhh[512 + c0 + 128];

  const float* gp[4];
  float* op[4];
  float* hp[4];
#pragma unroll
  for (int i = 0; i < 4; i++){
    int row = b0 + kgrp * 4 + i;
    gp[i] = gi + (size_t)row * tcnt * G3;
    op[i] = outp + (size_t)row * tcnt * ldo + ooff;
    hp[i] = hstate + (size_t)row * H_SZ;
  }

  float hreg[2][4];
#pragma unroll
  for (int j = 0; j < 2; j++)
#pragma unroll
    for (int i = 0; i < 4; i++){
      float v = hp[i][c0 + j * 128];
      hreg[j][i] = v;
      int r = kgrp * 4 + i;
      int off = ((c0 + j * 128) * 2) ^ ((r & 7) << 4);
      short h_, l_; cvt_hilo(v, h_, l_);
      *(short*)((char*)hhi[0] + r * 512 + off) = h_;
      *(short*)((char*)hlo[0] + r * 512 + off) = l_;
    }
  __syncthreads();

  const f32x4 zero = {0.f, 0.f, 0.f, 0.f};
  int cur = 0;
  for (int t = 0; t < tcnt; t++){
    // gi loads issued early (hide under MFMA phase)
    float gr_[2][4], gz_[2][4], gn_[2][4];
#pragma unroll
    for (int j = 0; j < 2; j++)
#pragma unroll
      for (int i = 0; i < 4; i++){
        const float* g = gp[i] + (size_t)t * G3 + c0 + j * 128;
        gr_[j][i] = g[0];
        gz_[j][i] = g[256];
        gn_[j][i] = g[512];
      }

    f32x4 acc[6];
#pragma unroll
    for (int q = 0; q < 6; q++) acc[q] = zero;
    const char* hhip = (const char*)hhi[cur] + arow * 512;
    const char* hlop = (const char*)hlo[cur] + arow * 512;
#pragma unroll
    for (int kt = 0; kt < 8; kt++){
      int kb = (kt * 64 + kgrp * 16) ^ hswz;
      bf16x8 ah = as_bf(*(const short8*)(hhip + kb));
      bf16x8 al = as_bf(*(const short8*)(hlop + kb));
#pragma unroll
      for (int q = 0; q < 6; q++){
        int bo = (((w + 8 * q) * 8 + kt) * 64 + lane) * 8;
        bf16x8 bh = as_bf(*(const short8*)(Whi + bo));
        acc[q] = MFMA_BF16(ah, bh, acc[q], 0, 0, 0);
        acc[q] = MFMA_BF16(al, bh, acc[q], 0, 0, 0);
      }
    }

    int nb = cur ^ 1;
#pragma unroll
    for (int j = 0; j < 2; j++)
#pragma unroll
      for (int i = 0; i < 4; i++){
        float rr = sigm(gr_[j][i] + acc[0 + j][i]);
        float zz = sigm(gz_[j][i] + acc[2 + j][i]);
        float bn = j ? bn1 : bn0;
        float nn = tanh_(gn_[j][i] + rr * (acc[4 + j][i] + bn));
        float hnew = (1.0f - zz) * nn + zz * hreg[j][i];
        hreg[j][i] = hnew;
        op[i][(size_t)t * ldo + c0 + j * 128] = hnew;
        int r = kgrp * 4 + i;
        int off = ((c0 + j * 128) * 2) ^ ((r & 7) << 4);
        short h_, l_; cvt_hilo(hnew, h_, l_);
        *(short*)((char*)hhi[nb] + r * 512 + off) = h_;
        *(short*)((char*)hlo[nb] + r * 512 + off) = l_;
      }
    __syncthreads();
    cur ^= 1;
  }

#pragma unroll
  for (int j = 0; j < 2; j++)
#pragma unroll
    for (int i = 0; i < 4; i++)
      hp[i][c0 + j * 128] = hreg[j][i];
}

// ---------- attention scores for a chunk ----------
__global__ __launch_bounds__(256, 1) void attn_scores(
    const float* __restrict__ outi, const float* __restrict__ Wv,
    const float* __restrict__ bv, const float* __restrict__ wu,
    float* __restrict__ sc, int t0, int tcnt)
{
  __shared__ float swv[A_SZ * H_SZ];
  __shared__ float sbu[A_SZ], sbv[A_SZ];
  int tid = threadIdx.x;
  for (int i = tid; i < A_SZ * H_SZ; i += 256) swv[i] = Wv[i];
  if (tid < A_SZ){ sbu[tid] = wu[tid]; sbv[tid] = bv[tid]; }
  __syncthreads();
  int r = blockIdx.x * 256 + tid;      // chunk-local row
  int b = r / tcnt;
  int tc = r - b * tcnt;
  const float* x = outi + (size_t)r * H_SZ;
  float acc[A_SZ];
#pragma unroll
  for (int a = 0; a < A_SZ; a++) acc[a] = 0.f;
  for (int h = 0; h < H_SZ; h += 4){
    f32x4 xv = *(const f32x4*)(x + h);
#pragma unroll
    for (int a = 0; a < A_SZ; a++){
      f32x4 w = *(const f32x4*)(swv + a * H_SZ + h);
      acc[a] += xv[0]*w[0] + xv[1]*w[1] + xv[2]*w[2] + xv[3]*w[3];
    }
  }
  float s = 0.f;
#pragma unroll
  for (int a = 0; a < A_SZ; a++) s += sbu[a] * tanh_(acc[a] + sbv[a]);
  sc[(size_t)b * T_SZ + t0 + tc] = s;
}

// ---------- online (unnormalized) context accumulation ----------
// |score| <= sum|wu| ~ 1.6 so exp() is safe without max-subtraction.
__global__ __launch_bounds__(256, 1) void attn_acc(
    const float* __restrict__ outi, const float* __restrict__ sc,
    int t0, int tcnt, float* __restrict__ ctx, float* __restrict__ lsum)
{
  int b = blockIdx.x, tid = threadIdx.x;
  float acc = ctx[(size_t)b * H_SZ + tid];
  const float* xp = outi + (size_t)b * tcnt * H_SZ + tid;
  float ls = 0.f;
  for (int tc = 0; tc < tcnt; tc++){
    float e = __expf(sc[(size_t)b * T_SZ + t0 + tc]);
    acc += e * xp[(size_t)tc * H_SZ];
    ls += e;
  }
  ctx[(size_t)b * H_SZ + tid] = acc;
  if (tid == 0) lsum[b] += ls;
}

__global__ __launch_bounds__(256, 1) void attn_fin(
    const float* __restrict__ ctx, const float* __restrict__ lsum,
    float* __restrict__ out)
{
  int b = blockIdx.x, tid = threadIdx.x;
  out[(size_t)b * H_SZ + tid] = ctx[(size_t)b * H_SZ + tid] / lsum[b];
}

// ---------- host ----------
extern "C" void kernel_launch(void* const* d_in, const int* in_sizes, int n_in,
                              void* d_out, int out_size, void* d_ws, size_t ws_size,
                              hipStream_t stream)
{
  (void)in_sizes; (void)n_in; (void)out_size;
  const float* crime = (const float*)d_in[0];
  const float* anom  = (const float*)d_in[1];
  const float* WihC = (const float*)d_in[2];
  const float* WhhC = (const float*)d_in[3];
  const float* bihC = (const float*)d_in[4];
  const float* bhhC = (const float*)d_in[5];
  const float* WihA = (const float*)d_in[6];
  const float* WhhA = (const float*)d_in[7];
  const float* bihA = (const float*)d_in[8];
  const float* bhhA = (const float*)d_in[9];
  const float* WihI = (const float*)d_in[10];
  const float* WhhI = (const float*)d_in[11];
  const float* bihI = (const float*)d_in[12];
  const float* bhhI = (const float*)d_in[13];
  const float* Wv = (const float*)d_in[14];
  const float* bv = (const float*)d_in[15];
  const float* wu = (const float*)d_in[16];
  float* out = (float*)d_out;

  char* ws = (char*)d_ws;
  size_t off = 0;
  auto take = [&](size_t n){ size_t r = off; off += (n + 255) & ~(size_t)255; return r; };

  short* pWihC_h = (short*)(ws + take((size_t)G3 * 128 * 2));
  short* pWihC_l = (short*)(ws + take((size_t)G3 * 128 * 2));
  short* pWhhC_h = (short*)(ws + take((size_t)G3 * 256 * 2));
  short* pWhhC_l = (short*)(ws + take((size_t)G3 * 256 * 2));
  short* pWihA_h = (short*)(ws + take((size_t)G3 * 96 * 2));
  short* pWihA_l = (short*)(ws + take((size_t)G3 * 96 * 2));
  short* pWhhA_h = (short*)(ws + take((size_t)G3 * 256 * 2));
  short* pWhhA_l = (short*)(ws + take((size_t)G3 * 256 * 2));
  short* pWihI_h = (short*)(ws + take((size_t)G3 * 512 * 2));
  short* pWihI_l = (short*)(ws + take((size_t)G3 * 512 * 2));
  short* pWhhI_h = (short*)(ws + take((size_t)G3 * 256 * 2));
  short* pWhhI_l = (short*)(ws + take((size_t)G3 * 256 * 2));
  float* scores  = (float*)(ws + take((size_t)B_SZ * T_SZ * 4));

  size_t state_off = off;
  float* hsC  = (float*)(ws + take((size_t)B_SZ * H_SZ * 4));
  float* hsA  = (float*)(ws + take((size_t)B_SZ * H_SZ * 4));
  float* hsI  = (float*)(ws + take((size_t)B_SZ * H_SZ * 4));
  float* ctx  = (float*)(ws + take((size_t)B_SZ * H_SZ * 4));
  float* lsum = (float*)(ws + take((size_t)B_SZ * 4));
  size_t state_end = off;

  // adaptive T-chunk: Gc(768) + Ga(768) + Oca(512) + Oi(256) per timestep
  size_t per = (size_t)B_SZ * 4 * (G3 + G3 + 512 + H_SZ);   // 18.87 MB per timestep
  size_t avail = (ws_size > off + 4096) ? (ws_size - off - 4096) : 0;
  int TC = (int)(avail / per);
  if (TC < 1) TC = 1;
  if (TC > T_SZ) TC = T_SZ;

  float* Gc  = (float*)(ws + take((size_t)B_SZ * TC * G3 * 4));
  float* Ga  = (float*)(ws + take((size_t)B_SZ * TC * G3 * 4));
  float* Oca = (float*)(ws + take((size_t)B_SZ * TC * 512 * 4));
  float* Oi  = (float*)(ws + take((size_t)B_SZ * TC * H_SZ * 4));

  // zero h-states, ctx, lsum
  zinit<<<2048, 256, 0, stream>>>((float*)(ws + state_off), (state_end - state_off) / 4);

  // pack weights (hi/lo bricks; gemms/gru consume hi only)
  packw_k<<<48 * 4,  64, 0, stream>>>(WihC, 128, pWihC_h, pWihC_l);
  packw_k<<<48 * 8,  64, 0, stream>>>(WhhC, 256, pWhhC_h, pWhhC_l);
  packw_k<<<48 * 3,  64, 0, stream>>>(WihA,  96, pWihA_h, pWihA_l);
  packw_k<<<48 * 8,  64, 0, stream>>>(WhhA, 256, pWhhA_h, pWhhA_l);
  packw_k<<<48 * 16, 64, 0, stream>>>(WihI, 512, pWihI_h, pWihI_l);
  packw_k<<<48 * 8,  64, 0, stream>>>(WhhI, 256, pWhhI_h, pWhhI_l);

  for (int t0 = 0; t0 < T_SZ; ){
    int tcnt = T_SZ - t0 < TC ? T_SZ - t0 : TC;
    int rows = B_SZ * tcnt;
    // input projections for both leaf GRUs
    gemm2p<<<rows / 64, 512, 0, stream>>>(crime, 128, T_SZ, t0, tcnt,
                                          pWihC_h, bihC, bhhC, Gc);
    gemm2p<<<rows / 64, 512, 0, stream>>>(anom, 96, T_SZ, t0, tcnt,
                                          pWihA_h, bihA, bhhA, Ga);
    // fused crime+anomaly recurrence: 256 WGs (all CUs)
    gru_rec2<<<256, 512, 0, stream>>>(
        Gc, pWhhC_h, bhhC, Oca, 512, 0,   hsC,
        Ga, pWhhA_h, bhhA, Oca, 512, 256, hsA,
        128, tcnt);
    // inter projection (reuses Gc for gi_i) + recurrence
    gemm2p<<<rows / 64, 512, 0, stream>>>(Oca, 512, 0, 0, tcnt,
                                          pWihI_h, bihI, bhhI, Gc);
    gru_rec2<<<128, 512, 0, stream>>>(
        Gc, pWhhI_h, bhhI, Oi, 256, 0, hsI,
        Gc, pWhhI_h, bhhI, Oi, 256, 0, hsI,
        128, tcnt);
    // attention: scores + online context accumulation
    attn_scores<<<rows / 256, 256, 0, stream>>>(Oi, Wv, bv, wu, scores, t0, tcnt);
    attn_acc<<<B_SZ, 256, 0, stream>>>(Oi, scores, t0, tcnt, ctx, lsum);
    t0 += tcnt;
  }
  attn_fin<<<B_SZ, 256, 0, stream>>>(ctx, lsum, out);
}